// Round 6
// baseline (1508.909 us; speedup 1.0000x reference)
//
#include <hip/hip_runtime.h>
#include <cstdint>

#define DD 256
#define TT 2048
#define KK 8192
#define NN 32768
#define QQ 8388608
#define PCAP 262144          // 32768 rows x <=8 pairs: cannot overflow
typedef unsigned long long u64;

typedef __attribute__((ext_vector_type(8))) short short8;   // 8 bf16
typedef __attribute__((ext_vector_type(4))) float f32x4;    // MFMA C/D

#define GLOBAL_AS __attribute__((address_space(1)))
#define LDS_AS    __attribute__((address_space(3)))

__device__ __forceinline__ void async_copy16(void* l, const void* g) {
    __builtin_amdgcn_global_load_lds((const GLOBAL_AS unsigned int*)g,
                                     (LDS_AS unsigned int*)l, 16, 0, 0);
}
__device__ __forceinline__ unsigned mapf(float f) {
    unsigned u = __float_as_uint(f);
    return (u & 0x80000000u) ? ~u : (u | 0x80000000u);
}
__device__ __forceinline__ float unmapf(unsigned u) {
    return __uint_as_float((u & 0x80000000u) ? (u & 0x7FFFFFFFu) : ~u);
}
__device__ __forceinline__ unsigned bf16_rne(float v) {
    unsigned ui = __float_as_uint(v);
    return (ui + 0x7FFFu + ((ui >> 16) & 1)) >> 16;
}

// ---------------------------------------------------------------------------
// prep: A32[n]=fp32(fp64 ||z_n||^2), R32[n]=||z_n - bf16(z_n)|| bound; init.
// ---------------------------------------------------------------------------
__global__ __launch_bounds__(256) void k_prepA(const float* __restrict__ z,
                                               float* __restrict__ A32,
                                               float* __restrict__ R32,
                                               int* __restrict__ cnt,
                                               int* __restrict__ cnt2,
                                               unsigned* __restrict__ em2,
                                               unsigned* __restrict__ elm2,
                                               float* __restrict__ out) {
    __shared__ double sd[256], sr[256];
    int tid = threadIdx.x;
    int r = tid & 63, c = tid >> 6;
    int n = blockIdx.x * 64 + r;
    if (blockIdx.x == 0 && tid == 0) {
        *cnt = 0; *cnt2 = 0; *em2 = 0u; *elm2 = 0u; out[QQ] = 0.0f;
    }
    int b = n >> 11, t = n & 2047;
    const float* zp = z + (size_t)b * 524288 + t;
    double s = 0.0, sq = 0.0;
#pragma unroll 8
    for (int i = 0; i < 64; i++) {
        float v  = zp[(size_t)(c * 64 + i) * 2048];
        float hf = __uint_as_float(bf16_rne(v) << 16);
        float rd = v - hf;                       // exact (Sterbenz)
        s  = fma((double)v,  (double)v,  s);
        sq = fma((double)rd, (double)rd, sq);
    }
    sd[tid] = s; sr[tid] = sq;
    __syncthreads();
    if (c == 0) {
        double ta = sd[r] + sd[64 + r] + sd[128 + r] + sd[192 + r];
        double tr = sr[r] + sr[64 + r] + sr[128 + r] + sr[192 + r];
        A32[n] = (float)ta;
        R32[n] = (float)sqrt(tr) * 1.0001f + 1e-9f;
    }
}

// ---------------------------------------------------------------------------
// z [b][d][t] -> zh [n][d] bf16 (hi only). grid 2048 x 256
// ---------------------------------------------------------------------------
__global__ __launch_bounds__(256) void k_convZ(const float* __restrict__ z,
                                               unsigned short* __restrict__ zh) {
    __shared__ float sm[64][65];
    int tid = threadIdx.x, bid = blockIdx.x;
    int b = bid >> 7, dt = (bid >> 5) & 3, tt = bid & 31;
    const float* zp = z + (size_t)b * 524288 + (size_t)dt * 131072 + tt * 64;
#pragma unroll
    for (int i = 0; i < 16; i++) {
        int idx = tid + 256 * i;
        int d = idx >> 6, t = idx & 63;
        sm[d][t] = zp[(size_t)d * 2048 + t];
    }
    __syncthreads();
    int d0 = (tid & 7) * 8;
#pragma unroll
    for (int i = 0; i < 2; i++) {
        int t = (tid >> 3) + 32 * i;
        size_t o = ((size_t)(b * 2048 + tt * 64 + t)) * 256 + dt * 64 + d0;
        short8 hv;
#pragma unroll
        for (int j = 0; j < 8; j++) hv[j] = (short)bf16_rne(sm[d0 + j][t]);
        *(short8*)(zh + o) = hv;
    }
}

// ---------------------------------------------------------------------------
// emb -> eh bf16; track max ||e||^2 and max ||e-eh||^2. wave per code.
// ---------------------------------------------------------------------------
__global__ __launch_bounds__(256) void k_convE(const float* __restrict__ emb,
                                               unsigned short* __restrict__ eh,
                                               unsigned* __restrict__ em2,
                                               unsigned* __restrict__ elm2) {
    int k    = blockIdx.x * 4 + (threadIdx.x >> 6);   // grid 2048 -> [0,8192)
    int lane = threadIdx.x & 63;
    float4 v = ((const float4*)(emb + (size_t)k * 256))[lane];
    float vv[4] = {v.x, v.y, v.z, v.w};
    float e2 = 0.f, r2 = 0.f;
    unsigned short hs[4];
#pragma unroll
    for (int j = 0; j < 4; j++) {
        unsigned hb = bf16_rne(vv[j]);
        float hf = __uint_as_float(hb << 16);
        float rd = vv[j] - hf;
        e2 = fmaf(vv[j], vv[j], e2);
        r2 = fmaf(rd, rd, r2);
        hs[j] = (unsigned short)hb;
    }
    uint2 pk;
    pk.x = (unsigned)hs[0] | ((unsigned)hs[1] << 16);
    pk.y = (unsigned)hs[2] | ((unsigned)hs[3] << 16);
    ((uint2*)(eh + (size_t)k * 256))[lane] = pk;
    for (int off = 32; off; off >>= 1) {
        e2 += __shfl_down(e2, off, 64);
        r2 += __shfl_down(r2, off, 64);
    }
    if (lane == 0) {
        atomicMax(em2,  __float_as_uint(e2 * 1.001f + 1e-12f));
        atomicMax(elm2, __float_as_uint(r2 * 1.01f  + 1e-16f));
    }
}

// ---------------------------------------------------------------------------
// h-only MFMA GEMM: maximize acc = zh.eh (argmin of -2acc). Block 256 rows x
// 1024 codes (8 slabs of 128); 4 waves x 64 rows. grid 1024 (mt=bid&127, ng=bid>>7).
// Emits per (row, ng): packed (score,idx) top-1 and (score) top-2.
// ---------------------------------------------------------------------------
__global__ __launch_bounds__(256, 2) void k_gemm(const unsigned short* __restrict__ zh,
                                                 const unsigned short* __restrict__ eh,
                                                 u64* __restrict__ cand) {
    __shared__ __align__(16) unsigned short Azh[8192];   // 16 tiles x 1 KB
    __shared__ __align__(16) unsigned short Beh[4096];   // 8 tiles x 1 KB
    __shared__ u64 rtop[512];                            // 256 rows x 2

    int tid = threadIdx.x, w = tid >> 6, lane = tid & 63;
    int lm = lane & 15, q = lane >> 4;
    int bid = blockIdx.x, mt = bid & 127, ng = bid >> 7;
    int srow = lane & 15, schunk = lane >> 4;

    const unsigned short* Ah = zh + (size_t)mt * 65536;

    float tb1[4][4], tb2[4][4];
    int   ti1[4][4];
#pragma unroll
    for (int mi = 0; mi < 4; mi++)
#pragma unroll
        for (int r = 0; r < 4; r++) { tb1[mi][r] = -3.4e38f; tb2[mi][r] = -3.4e38f; ti1[mi][r] = 0; }

    for (int ns = 0; ns < 8; ns++) {
        int n0 = ng * 1024 + ns * 128;
        const unsigned short* Bh = eh + (size_t)n0 * 256;

        f32x4 acc[4][8];
#pragma unroll
        for (int mi = 0; mi < 4; mi++)
#pragma unroll
            for (int ni = 0; ni < 8; ni++) acc[mi][ni] = (f32x4){0.f, 0.f, 0.f, 0.f};

        for (int kc = 0; kc < 8; kc++) {
            int koff = kc * 32 + schunk * 8;
            __syncthreads();
#pragma unroll
            for (int j = 0; j < 4; j++) {
                int at = 4 * w + j;
                async_copy16(&Azh[at * 512], Ah + (size_t)(at * 16 + srow) * 256 + koff);
            }
#pragma unroll
            for (int j = 0; j < 2; j++) {
                int bt = 2 * w + j;
                async_copy16(&Beh[bt * 512], Bh + (size_t)(bt * 16 + srow) * 256 + koff);
            }
            __syncthreads();
            short8 af[4];
#pragma unroll
            for (int mi = 0; mi < 4; mi++)
                af[mi] = *(const short8*)&Azh[(4 * w + mi) * 512 + lane * 8];
#pragma unroll
            for (int ni = 0; ni < 8; ni++) {
                short8 bf = *(const short8*)&Beh[ni * 512 + lane * 8];
#pragma unroll
                for (int mi = 0; mi < 4; mi++)
                    acc[mi][ni] = __builtin_amdgcn_mfma_f32_16x16x32_bf16(af[mi], bf, acc[mi][ni], 0, 0, 0);
            }
        }
        // top-2 scan in acc space (max). med3 trick: b2' = max(min(v,b1), b2)
#pragma unroll
        for (int mi = 0; mi < 4; mi++)
#pragma unroll
            for (int reg = 0; reg < 4; reg++) {
                float b1 = tb1[mi][reg], b2 = tb2[mi][reg];
                int   i1 = ti1[mi][reg];
#pragma unroll
                for (int ni = 0; ni < 8; ni++) {
                    float v = acc[mi][ni][reg];
                    int code = n0 + ni * 16 + lm;
                    b2 = fmaxf(fminf(v, b1), b2);
                    if (v > b1) { b1 = v; i1 = code; }   // strict: keeps lowest idx
                }
                tb1[mi][reg] = b1; tb2[mi][reg] = b2; ti1[mi][reg] = i1;
            }
    }

    // butterfly over the 16 lm-lanes; owner (lm==0) writes its row
#pragma unroll
    for (int mi = 0; mi < 4; mi++)
#pragma unroll
        for (int reg = 0; reg < 4; reg++) {
            float b1 = tb1[mi][reg], b2 = tb2[mi][reg];
            int   i1 = ti1[mi][reg];
#pragma unroll
            for (int msk = 1; msk <= 8; msk <<= 1) {
                float o1 = __shfl_xor(b1, msk, 64);
                float o2 = __shfl_xor(b2, msk, 64);
                int   oi = __shfl_xor(i1, msk, 64);
                float lo = fminf(b1, o1);
                bool take = (o1 > b1) || (o1 == b1 && oi < i1);
                b2 = fmaxf(lo, fmaxf(b2, o2));
                if (take) { b1 = o1; i1 = oi; }
            }
            if (lm == 0) {
                int row = w * 64 + mi * 16 + q * 4 + reg;
                rtop[row * 2]     = ((u64)mapf(-2.0f * b1) << 32) | (unsigned)i1;
                rtop[row * 2 + 1] = ((u64)mapf(-2.0f * b2) << 32);
            }
        }
    __syncthreads();
    size_t o = ((size_t)ng * 32768 + (size_t)mt * 256) * 2;
    cand[o + tid]       = rtop[tid];
    cand[o + 256 + tid] = rtop[256 + tid];
}

// ---------------------------------------------------------------------------
// select: merge 8 ngs; certify / emit pairs / flag row. grid 128
// ---------------------------------------------------------------------------
__global__ __launch_bounds__(256) void k_select(const u64* __restrict__ cand,
                                                const float* __restrict__ A32,
                                                const float* __restrict__ R32,
                                                const unsigned* __restrict__ em2,
                                                const unsigned* __restrict__ elm2,
                                                int* __restrict__ keys,
                                                u64* __restrict__ keys2,
                                                int* __restrict__ cnt,
                                                int* __restrict__ rlist,
                                                int* __restrict__ cnt2,
                                                unsigned* __restrict__ plist) {
    int n = blockIdx.x * 256 + threadIdx.x;
    float Em  = sqrtf(__uint_as_float(*em2));
    float ELm = sqrtf(__uint_as_float(*elm2));

    u64 e1[8];
    u64 best = ~0ull;
    float p2min = 3.4e38f;
#pragma unroll
    for (int j = 0; j < 8; j++) {
        u64 c1 = cand[((size_t)j * 32768 + n) * 2];
        u64 c2 = cand[((size_t)j * 32768 + n) * 2 + 1];
        e1[j] = c1;
        best = (c1 < best) ? c1 : best;
        float f2 = unmapf((unsigned)(c2 >> 32));
        p2min = fminf(p2min, f2);
    }
    float bf = unmapf((unsigned)(best >> 32));
    keys[n]  = (int)(unsigned)(best & 0xFFFFFFFFull);
    keys2[n] = ~0ull;

    float A = A32[n], R = R32[n];
    float ZH = sqrtf(A) + R + 0.01f;
    float W  = (A >= 255.9f) ? 3.4e-5f : 1.8e-5f;
    float m  = 4.0f * (ZH * ELm + R * Em) + W + 4e-6f;
    float thr = bf + m;

    bool flag = (p2min <= thr);
    int ccount = 0;
    int codes[8];
#pragma unroll
    for (int j = 0; j < 8; j++) {
        float f1 = unmapf((unsigned)(e1[j] >> 32));
        if (f1 <= thr) codes[ccount++] = (int)(unsigned)(e1[j] & 0xFFFFFFFFull);
    }
    if (flag) {
        int p = atomicAdd(cnt, 1);
        rlist[p] = n;
    } else if (ccount >= 2) {
        int base = atomicAdd(cnt2, ccount);
        for (int i = 0; i < ccount; i++)
            plist[base + i] = (unsigned)(n * 8192 + codes[i]);
    }
}

// ---------------------------------------------------------------------------
// rescore: exact np-fp32 chain per (row, code) pair; atomicMin packed. grid 64
// ---------------------------------------------------------------------------
__global__ __launch_bounds__(256) void k_rescore(const float* __restrict__ z,
                                                 const float* __restrict__ emb,
                                                 const float* __restrict__ A32,
                                                 const unsigned* __restrict__ plist,
                                                 const int* __restrict__ cnt2,
                                                 u64* __restrict__ keys2) {
    int total = *cnt2;
    for (int p = blockIdx.x * 256 + threadIdx.x; p < total; p += gridDim.x * 256) {
        unsigned e = plist[p];
        int n = e >> 13, k = e & 8191;
        int b = n >> 11, t = n & 2047;
        const float* zp = z + (size_t)b * 524288 + t;
        const float* ep = emb + (size_t)k * 256;
        float acc = 0.0f;
#pragma unroll 8
        for (int d = 0; d < 256; d++)
            acc = fmaf(zp[(size_t)d * 2048], ep[d], acc);
        float dk = A32[n] - 2.0f * acc;
        u64 pk = ((u64)mapf(dk) << 32) | (unsigned)k;
        atomicMin(&keys2[n], pk);
    }
}

// ---------------------------------------------------------------------------
// refine: full-row exact np-fp32 emulation for flagged rows (r3-proven). grid 512
// ---------------------------------------------------------------------------
__global__ __launch_bounds__(256) void k_refine(const float* __restrict__ z,
                                                const float* __restrict__ emb,
                                                const float* __restrict__ A32,
                                                const int* __restrict__ list,
                                                const int* __restrict__ cnt,
                                                int* __restrict__ keys) {
    __shared__ __align__(16) float zs[256][8];
    __shared__ float aA[8];
    __shared__ int   ln[8];
    __shared__ u64   wred[4 * 8];

    int tid = threadIdx.x, lane = tid & 63, w = tid >> 6;
    int count = *cnt;
    int ngroups = (count + 7) >> 3;

    for (int g = blockIdx.x; g < ngroups; g += gridDim.x) {
        __syncthreads();
#pragma unroll
        for (int r = 0; r < 8; r++) {
            int row = g * 8 + r;
            int n   = list[(row < count) ? row : 0];
            int b = n >> 11, t = n & 2047;
            zs[tid][r] = z[(size_t)b * 524288 + (size_t)tid * 2048 + t];
            if (tid == 0) { ln[r] = (row < count) ? n : -1; aA[r] = A32[n]; }
        }
        __syncthreads();

        u64 best[8];
#pragma unroll
        for (int r = 0; r < 8; r++) best[r] = 0xFFFFFFFFFFFFFFFFull;
        float Ar[8];
#pragma unroll
        for (int r = 0; r < 8; r++) Ar[r] = aA[r];

        for (int c = 0; c < 8; c++) {
            int kbase = c * 1024 + tid;
            const float4* e0 = (const float4*)(emb + (size_t)(kbase)       * 256);
            const float4* e1 = (const float4*)(emb + (size_t)(kbase + 256) * 256);
            const float4* e2 = (const float4*)(emb + (size_t)(kbase + 512) * 256);
            const float4* e3 = (const float4*)(emb + (size_t)(kbase + 768) * 256);
            float acc[4][8];
#pragma unroll
            for (int qq = 0; qq < 4; qq++)
#pragma unroll
                for (int r = 0; r < 8; r++) acc[qq][r] = 0.0f;

            for (int d4 = 0; d4 < 64; d4++) {
                float4 v0 = e0[d4], v1 = e1[d4], v2 = e2[d4], v3 = e3[d4];
                const float* p0 = (const float*)&v0;
                const float* p1 = (const float*)&v1;
                const float* p2 = (const float*)&v2;
                const float* p3 = (const float*)&v3;
#pragma unroll
                for (int i = 0; i < 4; i++) {
                    int d = 4 * d4 + i;
                    float4 za  = *(const float4*)&zs[d][0];
                    float4 zb2 = *(const float4*)&zs[d][4];
                    const float* zr  = (const float*)&za;
                    const float* zr2 = (const float*)&zb2;
#pragma unroll
                    for (int r = 0; r < 4; r++) {
                        acc[0][r]     = fmaf(zr[r],  p0[i], acc[0][r]);
                        acc[1][r]     = fmaf(zr[r],  p1[i], acc[1][r]);
                        acc[2][r]     = fmaf(zr[r],  p2[i], acc[2][r]);
                        acc[3][r]     = fmaf(zr[r],  p3[i], acc[3][r]);
                        acc[0][r + 4] = fmaf(zr2[r], p0[i], acc[0][r + 4]);
                        acc[1][r + 4] = fmaf(zr2[r], p1[i], acc[1][r + 4]);
                        acc[2][r + 4] = fmaf(zr2[r], p2[i], acc[2][r + 4]);
                        acc[3][r + 4] = fmaf(zr2[r], p3[i], acc[3][r + 4]);
                    }
                }
            }
#pragma unroll
            for (int qq = 0; qq < 4; qq++) {
                int k = kbase + qq * 256;
#pragma unroll
                for (int r = 0; r < 8; r++) {
                    float dk = Ar[r] - 2.0f * acc[qq][r];
                    u64 p = ((u64)mapf(dk) << 32) | (unsigned)k;
                    best[r] = (p < best[r]) ? p : best[r];
                }
            }
        }
#pragma unroll
        for (int r = 0; r < 8; r++) {
            u64 v = best[r];
            for (int off = 32; off; off >>= 1) {
                u64 o = __shfl_down(v, off, 64);
                v = (o < v) ? o : v;
            }
            if (lane == 0) wred[w * 8 + r] = v;
        }
        __syncthreads();
        if (tid < 8) {
            u64 v = wred[tid];
#pragma unroll
            for (int j = 1; j < 4; j++) {
                u64 o = wred[j * 8 + tid];
                v = (o < v) ? o : v;
            }
            int n = ln[tid];
            if (n >= 0) keys[n] = (int)(unsigned)(v & 0xFFFFFFFFull);
        }
        __syncthreads();
    }
}

// ---------------------------------------------------------------------------
// out: gather quantized, idx, loss = 1.25 * mean((q-z)^2). grid 128
// ---------------------------------------------------------------------------
__global__ __launch_bounds__(256) void k_out(const float* __restrict__ z,
                                             const float* __restrict__ emb,
                                             const int* __restrict__ keys,
                                             const u64* __restrict__ keys2,
                                             float* __restrict__ out) {
    int tid = threadIdx.x;
    int n = blockIdx.x * 256 + tid;
    int b = n >> 11, t = n & 2047;
    u64 k2 = keys2[n];
    int idx = (k2 != ~0ull) ? (int)(unsigned)(k2 & 0xFFFFFFFFull) : keys[n];
    out[QQ + 1 + n] = (float)idx;

    const float4* erow = (const float4*)(emb + (size_t)idx * 256);
    const float*  zp   = z   + (size_t)b * 524288 + t;
    float*        op   = out + (size_t)b * 524288 + t;

    float ssd = 0.0f;
#pragma unroll 4
    for (int d4 = 0; d4 < 64; d4++) {
        float4 qv = erow[d4];
        float qa[4] = {qv.x, qv.y, qv.z, qv.w};
#pragma unroll
        for (int r = 0; r < 4; r++) {
            int d = 4 * d4 + r;
            float zv = zp[(size_t)d * 2048];
            float df = qa[r] - zv;
            ssd = fmaf(df, df, ssd);
            op[(size_t)d * 2048] = qa[r];
        }
    }
    for (int off = 32; off; off >>= 1) ssd += __shfl_down(ssd, off, 64);
    __shared__ float red[4];
    if ((tid & 63) == 0) red[tid >> 6] = ssd;
    __syncthreads();
    if (tid == 0) {
        float tot = red[0] + red[1] + red[2] + red[3];
        atomicAdd(out + QQ, tot * (1.25f / (float)QQ));
    }
}

// ---------------------------------------------------------------------------
extern "C" void kernel_launch(void* const* d_in, const int* in_sizes, int n_in,
                              void* d_out, int out_size, void* d_ws, size_t ws_size,
                              hipStream_t stream) {
    const float* z   = (const float*)d_in[0];   // [16, 256, 2048]
    const float* emb = (const float*)d_in[1];   // [8192, 256]
    float* out = (float*)d_out;

    char* ws = (char*)d_ws;
    const size_t oZH = 0;                       // 16 MB
    const size_t oEH = oZH + 16777216;          // 4 MB
    const size_t oCD = oEH + 4194304;           // cand 8*32768*2*8 = 4 MB
    const size_t oA3 = oCD + 4194304;           // 128 KB
    const size_t oR3 = oA3 + 131072;            // 128 KB
    const size_t oKY = oR3 + 131072;            // 128 KB
    const size_t oK2 = oKY + 131072;            // 256 KB
    const size_t oRL = oK2 + 262144;            // 128 KB
    const size_t oPL = oRL + 131072;            // 1 MB
    const size_t oCN = oPL + 1048576;           // counters

    unsigned short* zh = (unsigned short*)(ws + oZH);
    unsigned short* eh = (unsigned short*)(ws + oEH);
    u64*      cand  = (u64*)(ws + oCD);
    float*    A32   = (float*)(ws + oA3);
    float*    R32   = (float*)(ws + oR3);
    int*      keys  = (int*)(ws + oKY);
    u64*      keys2 = (u64*)(ws + oK2);
    int*      rlist = (int*)(ws + oRL);
    unsigned* plist = (unsigned*)(ws + oPL);
    int*      cnt   = (int*)(ws + oCN);
    int*      cnt2  = (int*)(ws + oCN + 64);
    unsigned* em2   = (unsigned*)(ws + oCN + 128);
    unsigned* elm2  = (unsigned*)(ws + oCN + 192);

    k_prepA  <<<512,  256, 0, stream>>>(z, A32, R32, cnt, cnt2, em2, elm2, out);
    k_convZ  <<<2048, 256, 0, stream>>>(z, zh);
    k_convE  <<<2048, 256, 0, stream>>>(emb, eh, em2, elm2);
    k_gemm   <<<1024, 256, 0, stream>>>(zh, eh, cand);
    k_select <<<128,  256, 0, stream>>>(cand, A32, R32, em2, elm2, keys, keys2,
                                        cnt, rlist, cnt2, plist);
    k_rescore<<<64,   256, 0, stream>>>(z, emb, A32, plist, cnt2, keys2);
    k_refine <<<512,  256, 0, stream>>>(z, emb, A32, rlist, cnt, keys);
    k_out    <<<128,  256, 0, stream>>>(z, emb, keys, keys2, out);
}